// Round 4
// baseline (161.375 us; speedup 1.0000x reference)
//
#include <hip/hip_runtime.h>
#include <hip/hip_bf16.h>

typedef __attribute__((ext_vector_type(8))) short short8;
typedef __attribute__((ext_vector_type(4))) short short4v;
typedef __attribute__((ext_vector_type(4))) float floatx4;

#define SEQ   2048
#define EMB   1024
#define HEAD  64
#define BATCH 8

__device__ __forceinline__ short f2bf(float f) {
    union { float f; unsigned u; } a; a.f = f;
    unsigned u = a.u;
    u = (u + 0x7FFFu + ((u >> 16) & 1u)) >> 16;   // round-to-nearest-even
    return (short)u;
}

// Wf: MFMA-fragment-ordered weights, bf16.
// fragid f = (mat*4 + nt)*32 + kchunk  (kchunk = k0/32), mat 0=Wq 1=Wk 2=Wv.
// Wf[f*512 + lane*8 + j] = W[k = kchunk*32 + (lane>>4)*8 + j][h = nt*16 + (lane&15)]
__global__ void wtrans_kernel(const float* __restrict__ Wk,
                              const float* __restrict__ Wq,
                              const float* __restrict__ Wv,
                              short* __restrict__ Wf) {
    int gid  = blockIdx.x * 256 + threadIdx.x;   // 24576 total
    int lane = gid & 63;
    int fid  = gid >> 6;                          // 0..383
    int chunk = fid & 31;
    int mnt  = fid >> 5;                          // mat*4+nt
    int mat  = mnt >> 2, nt = mnt & 3;
    const float* src = (mat == 0) ? Wq : (mat == 1) ? Wk : Wv;
    int n = lane & 15, quad = lane >> 4;
    int h = nt * 16 + n;
    short8 o8;
    #pragma unroll
    for (int j = 0; j < 8; ++j) {
        int kk = chunk * 32 + quad * 8 + j;
        o8[j] = f2bf(src[kk * 64 + h]);
    }
    *(short8*)(Wf + (long)gid * 8) = o8;
}

// Block: 16 rows x 192 cols, 4 waves split K into quarters; LDS reduce.
// All 12 B-fragments batch-loaded per K-step so L2 latency is paid once/iter.
__global__ __launch_bounds__(256) void qkv_kernel(const float* __restrict__ x,
                                                  const short* __restrict__ Wf,
                                                  short* __restrict__ q,
                                                  short* __restrict__ k,
                                                  short* __restrict__ vt) {
    __shared__ float red[3][64][48];   // waves 1..3 partials
    const int wv   = threadIdx.x >> 6;
    const int lane = threadIdx.x & 63;
    const int l15  = lane & 15;
    const int quad = lane >> 4;
    const int row0 = blockIdx.x * 16;

    floatx4 acc[12];
    #pragma unroll
    for (int f = 0; f < 12; ++f) acc[f] = (floatx4){0.f, 0.f, 0.f, 0.f};

    const float* xrow = x + (long)(row0 + l15) * EMB + quad * 8;
    const int kbase = wv * 256;

    floatx4 xa = *(const floatx4*)(xrow + kbase);
    floatx4 xb = *(const floatx4*)(xrow + kbase + 4);

    #pragma unroll 1
    for (int kk = 0; kk < 256; kk += 32) {
        const int k0 = kbase + kk;
        // batch-load all 12 B fragments (independent -> overlapped L2 loads)
        short8 bfr[12];
        const short* wp = Wf + ((long)(k0 >> 5) * 64 + lane) * 8;
        #pragma unroll
        for (int f = 0; f < 12; ++f)
            bfr[f] = *(const short8*)(wp + (long)f * 32 * 64 * 8);
        // prefetch next x chunk (wraps on last iter -> safe, L1-hot)
        const int kn = kbase + ((kk + 32) & 255);
        floatx4 na = *(const floatx4*)(xrow + kn);
        floatx4 nb = *(const floatx4*)(xrow + kn + 4);

        short8 a;
        #pragma unroll
        for (int i = 0; i < 4; ++i) { a[i] = f2bf(xa[i]); a[4 + i] = f2bf(xb[i]); }
        #pragma unroll
        for (int f = 0; f < 12; ++f)
            acc[f] = __builtin_amdgcn_mfma_f32_16x16x32_bf16(a, bfr[f], acc[f], 0, 0, 0);
        xa = na; xb = nb;
    }

    if (wv > 0) {
        #pragma unroll
        for (int f = 0; f < 12; ++f)
            #pragma unroll
            for (int r = 0; r < 4; ++r)
                red[wv - 1][lane][f * 4 + r] = acc[f][r];
    }
    __syncthreads();
    if (wv == 0) {
        #pragma unroll
        for (int w = 0; w < 3; ++w)
            #pragma unroll
            for (int f = 0; f < 12; ++f)
                #pragma unroll
                for (int r = 0; r < 4; ++r)
                    acc[f][r] += red[w][lane][f * 4 + r];

        const int bidx = row0 >> 11;
        const int srow = (row0 & (SEQ - 1)) + quad * 4;
        #pragma unroll
        for (int nt = 0; nt < 4; ++nt) {
            const int col = nt * 16 + l15;
            #pragma unroll
            for (int r = 0; r < 4; ++r) {
                long grow = (long)(row0 + quad * 4 + r);
                q[grow * HEAD + col] = f2bf(acc[nt][r]);
                k[grow * HEAD + col] = f2bf(acc[4 + nt][r]);
            }
            short4v vv;
            #pragma unroll
            for (int r = 0; r < 4; ++r) vv[r] = f2bf(acc[8 + nt][r]);
            *(short4v*)(vt + ((long)bidx * HEAD + col) * SEQ + srow) = vv;
        }
    }
}

// Flash attention, causal, FIXED-BASE softmax (base M=16; causal diagonal
// guarantees row-max >= 0 so exp(s-16) never over/underflows harmfully;
// base cancels exactly in sum(pV)/sum(p)). No per-iter reductions, no
// per-iter __syncthreads (Plds is per-wave: wave-local lgkmcnt suffices).
__global__ __launch_bounds__(256) void attn_kernel(const short* __restrict__ q,
                                                   const short* __restrict__ k,
                                                   const short* __restrict__ vt,
                                                   float* __restrict__ out) {
    __shared__ short Plds[4][16][32];
    __shared__ float oA[4][16][64];
    __shared__ float lA[4][16];

    const int wv   = threadIdx.x >> 6;
    const int lane = threadIdx.x & 63;
    const int l15  = lane & 15;
    const int quad = lane >> 4;
    const int b    = blockIdx.x & 7;
    const int t    = 127 - (blockIdx.x >> 3);
    const int s0   = t * 16;

    const int nch  = (t + 2) >> 1;          // ceil(16(t+1)/32)
    const int c0   = (nch * wv) >> 2;
    const int c1   = (nch * (wv + 1)) >> 2;
    const int cmax = (nch + 3) >> 2;        // uniform loop count per block

    const short* qb = q + ((long)b * SEQ + s0 + l15) * HEAD + quad * 8;
    short8 qf0 = *(const short8*)(qb);
    short8 qf1 = *(const short8*)(qb + 32);

    floatx4 o[4];
    #pragma unroll
    for (int nt = 0; nt < 4; ++nt) o[nt] = (floatx4){0.f, 0.f, 0.f, 0.f};
    float l_i[4] = {0.f, 0.f, 0.f, 0.f};

    for (int i = 0; i < cmax; ++i) {
        const int c = c0 + i;
        const bool act = (c < c1);
        const int j0 = c * 32;              // always in-bounds

        // ---- S = Q K^T ----
        floatx4 sa[2];
        sa[0] = (floatx4){0.f, 0.f, 0.f, 0.f};
        sa[1] = (floatx4){0.f, 0.f, 0.f, 0.f};
        #pragma unroll
        for (int nt = 0; nt < 2; ++nt) {
            const short* kb = k + ((long)b * SEQ + j0 + nt * 16 + l15) * HEAD + quad * 8;
            short8 kf0 = *(const short8*)(kb);
            short8 kf1 = *(const short8*)(kb + 32);
            sa[nt] = __builtin_amdgcn_mfma_f32_16x16x32_bf16(qf0, kf0, sa[nt], 0, 0, 0);
            sa[nt] = __builtin_amdgcn_mfma_f32_16x16x32_bf16(qf1, kf1, sa[nt], 0, 0, 0);
        }

        // ---- p = exp(s/8 - 16), causal + activity mask; accumulate l ----
        #pragma unroll
        for (int r = 0; r < 4; ++r) {
            const int sq = s0 + quad * 4 + r;
            #pragma unroll
            for (int nt = 0; nt < 2; ++nt) {
                const int sk = j0 + nt * 16 + l15;
                float p = (!act || sk > sq) ? 0.f
                          : __expf(sa[nt][r] * 0.125f - 16.f);
                sa[nt][r] = p;
                l_i[r] += p;
            }
        }

        // ---- P: C-layout -> A-layout via per-wave LDS buffer ----
        #pragma unroll
        for (int nt = 0; nt < 2; ++nt)
            #pragma unroll
            for (int r = 0; r < 4; ++r)
                Plds[wv][quad * 4 + r][nt * 16 + l15] = f2bf(sa[nt][r]);
        short8 pf = *(const short8*)(&Plds[wv][l15][quad * 8]);

        // ---- O += P V ----
        #pragma unroll
        for (int nt = 0; nt < 4; ++nt) {
            const short* vb = vt + ((long)b * HEAD + nt * 16 + l15) * SEQ + j0 + quad * 8;
            short8 vf = *(const short8*)(vb);
            o[nt] = __builtin_amdgcn_mfma_f32_16x16x32_bf16(pf, vf, o[nt], 0, 0, 0);
        }
    }

    // ---- single end-of-loop l reduction (16 lanes sharing a quad) ----
    #pragma unroll
    for (int msk = 1; msk <= 8; msk <<= 1) {
        #pragma unroll
        for (int r = 0; r < 4; ++r)
            l_i[r] += __shfl_xor(l_i[r], msk, 64);
    }
    if (l15 == 0) {
        #pragma unroll
        for (int r = 0; r < 4; ++r) lA[wv][quad * 4 + r] = l_i[r];
    }
    #pragma unroll
    for (int nt = 0; nt < 4; ++nt)
        #pragma unroll
        for (int r = 0; r < 4; ++r)
            oA[wv][quad * 4 + r][nt * 16 + l15] = o[nt][r];
    __syncthreads();

    // ---- cooperative epilogue: sum 4 wave-partials, coalesced float4 out ----
    {
        const int idx = threadIdx.x * 4;         // 1024 outputs, 4 per thread
        const int row = idx >> 6;
        const int col = idx & 63;
        const float l = lA[0][row] + lA[1][row] + lA[2][row] + lA[3][row];
        const float inv = 1.f / l;
        floatx4 ov;
        #pragma unroll
        for (int j = 0; j < 4; ++j)
            ov[j] = (oA[0][row][col + j] + oA[1][row][col + j]
                   + oA[2][row][col + j] + oA[3][row][col + j]) * inv;
        *(floatx4*)(out + ((long)b * SEQ + s0 + row) * HEAD + col) = ov;
    }
}

extern "C" void kernel_launch(void* const* d_in, const int* in_sizes, int n_in,
                              void* d_out, int out_size, void* d_ws, size_t ws_size,
                              hipStream_t stream) {
    const float* x  = (const float*)d_in[0];
    const float* Wk = (const float*)d_in[1];
    const float* Wq = (const float*)d_in[2];
    const float* Wv = (const float*)d_in[3];
    float* out = (float*)d_out;

    short* Wf = (short*)d_ws;                          // 384 KiB
    short* q  = Wf + 3 * HEAD * EMB;                   // 2 MiB each
    short* k  = q + (long)BATCH * SEQ * HEAD;
    short* vt = k + (long)BATCH * SEQ * HEAD;

    hipLaunchKernelGGL(wtrans_kernel, dim3(96), dim3(256), 0, stream, Wk, Wq, Wv, Wf);
    hipLaunchKernelGGL(qkv_kernel, dim3(BATCH * SEQ / 16), dim3(256), 0, stream, x, Wf, q, k, vt);
    hipLaunchKernelGGL(attn_kernel, dim3(BATCH * 128), dim3(256), 0, stream, q, k, vt, out);
}

// Round 5
// 160.442 us; speedup vs baseline: 1.0058x; 1.0058x over previous
//
#include <hip/hip_runtime.h>
#include <hip/hip_bf16.h>

typedef __attribute__((ext_vector_type(8))) short short8;
typedef __attribute__((ext_vector_type(4))) short short4v;
typedef __attribute__((ext_vector_type(4))) float floatx4;

#define SEQ   2048
#define EMB   1024
#define HEAD  64
#define BATCH 8

__device__ __forceinline__ short f2bf(float f) {
    union { float f; unsigned u; } a; a.f = f;
    unsigned u = a.u;
    u = (u + 0x7FFFu + ((u >> 16) & 1u)) >> 16;   // round-to-nearest-even
    return (short)u;
}

// Wf: MFMA-fragment-ordered weights, bf16.
// fragid f = (mat*4 + nt)*32 + kchunk  (kchunk = k0/32), mat 0=Wq 1=Wk 2=Wv.
// Wf[f*512 + lane*8 + j] = W[k = kchunk*32 + (lane>>4)*8 + j][h = nt*16 + (lane&15)]
__global__ void wtrans_kernel(const float* __restrict__ Wk,
                              const float* __restrict__ Wq,
                              const float* __restrict__ Wv,
                              short* __restrict__ Wf) {
    int gid  = blockIdx.x * 256 + threadIdx.x;   // 24576 total
    int lane = gid & 63;
    int fid  = gid >> 6;                          // 0..383
    int chunk = fid & 31;
    int mnt  = fid >> 5;                          // mat*4+nt
    int mat  = mnt >> 2, nt = mnt & 3;
    const float* src = (mat == 0) ? Wq : (mat == 1) ? Wk : Wv;
    int n = lane & 15, quad = lane >> 4;
    int h = nt * 16 + n;
    short8 o8;
    #pragma unroll
    for (int j = 0; j < 8; ++j) {
        int kk = chunk * 32 + quad * 8 + j;
        o8[j] = f2bf(src[kk * 64 + h]);
    }
    *(short8*)(Wf + (long)gid * 8) = o8;
}

// Block: 16 rows x 192 cols, 4 waves split K into quarters; LDS reduce.
// launch_bounds(256,3): VGPR cap 170 so all 12 B-fragments stay live ->
// one L2 latency per iter instead of serialized groups (R4 VGPR=80 disease).
__global__ __launch_bounds__(256, 3) void qkv_kernel(const float* __restrict__ x,
                                                     const short* __restrict__ Wf,
                                                     short* __restrict__ q,
                                                     short* __restrict__ k,
                                                     short* __restrict__ vt) {
    __shared__ float red[3][64][50];   // stride 50: 2-way bank alias (free)
    const int wv   = threadIdx.x >> 6;
    const int lane = threadIdx.x & 63;
    const int l15  = lane & 15;
    const int quad = lane >> 4;
    const int row0 = blockIdx.x * 16;

    floatx4 acc[12];
    #pragma unroll
    for (int f = 0; f < 12; ++f) acc[f] = (floatx4){0.f, 0.f, 0.f, 0.f};

    const float* xrow = x + (long)(row0 + l15) * EMB + quad * 8;
    const short* wlane = Wf + (long)lane * 8;
    const int kbase = wv * 256;

    floatx4 xa = *(const floatx4*)(xrow + kbase);
    floatx4 xb = *(const floatx4*)(xrow + kbase + 4);

    #pragma unroll 1
    for (int kk = 0; kk < 256; kk += 32) {
        const int cidx = (kbase + kk) >> 5;
        // batch-load all 12 B fragments (independent, stay live in VGPRs)
        short8 bfr[12];
        #pragma unroll
        for (int f = 0; f < 12; ++f)
            bfr[f] = *(const short8*)(wlane + (long)(f * 32 + cidx) * 512);
        // prefetch next x chunk (wraps on last iter -> safe, L1-hot)
        const int kn = kbase + ((kk + 32) & 255);
        floatx4 na = *(const floatx4*)(xrow + kn);
        floatx4 nb = *(const floatx4*)(xrow + kn + 4);

        short8 a;
        #pragma unroll
        for (int i = 0; i < 4; ++i) { a[i] = f2bf(xa[i]); a[4 + i] = f2bf(xb[i]); }
        #pragma unroll
        for (int f = 0; f < 12; ++f)
            acc[f] = __builtin_amdgcn_mfma_f32_16x16x32_bf16(a, bfr[f], acc[f], 0, 0, 0);
        xa = na; xb = nb;
    }

    if (wv > 0) {
        #pragma unroll
        for (int f = 0; f < 12; ++f)
            #pragma unroll
            for (int r = 0; r < 4; ++r)
                red[wv - 1][lane][f * 4 + r] = acc[f][r];
    }
    __syncthreads();
    if (wv == 0) {
        #pragma unroll
        for (int w = 0; w < 3; ++w)
            #pragma unroll
            for (int f = 0; f < 12; ++f)
                #pragma unroll
                for (int r = 0; r < 4; ++r)
                    acc[f][r] += red[w][lane][f * 4 + r];

        const int bidx = row0 >> 11;
        const int srow = (row0 & (SEQ - 1)) + quad * 4;
        #pragma unroll
        for (int nt = 0; nt < 4; ++nt) {
            const int col = nt * 16 + l15;
            #pragma unroll
            for (int r = 0; r < 4; ++r) {
                long grow = (long)(row0 + quad * 4 + r);
                q[grow * HEAD + col] = f2bf(acc[nt][r]);
                k[grow * HEAD + col] = f2bf(acc[4 + nt][r]);
            }
            short4v vv;
            #pragma unroll
            for (int r = 0; r < 4; ++r) vv[r] = f2bf(acc[8 + nt][r]);
            *(short4v*)(vt + ((long)bidx * HEAD + col) * SEQ + srow) = vv;
        }
    }
}

// Flash attention, causal, fixed-base softmax (exp(s/8-16); causal diagonal
// guarantees row-max >= 0, base cancels in sum(pV)/sum(p)).
// K/V register double-buffer: next chunk prefetched at iter top so the QK
// MFMA never stalls on a fresh L2 round-trip.
__global__ __launch_bounds__(256, 3) void attn_kernel(const short* __restrict__ q,
                                                      const short* __restrict__ k,
                                                      const short* __restrict__ vt,
                                                      float* __restrict__ out) {
    __shared__ short Plds[4][16][32];
    __shared__ float oA[4][16][64];
    __shared__ float lA[4][16];

    const int wv   = threadIdx.x >> 6;
    const int lane = threadIdx.x & 63;
    const int l15  = lane & 15;
    const int quad = lane >> 4;
    const int b    = blockIdx.x & 7;
    const int t    = 127 - (blockIdx.x >> 3);
    const int s0   = t * 16;

    const int nch  = (t + 2) >> 1;          // ceil(16(t+1)/32)
    const int c0   = (nch * wv) >> 2;
    const int c1   = (nch * (wv + 1)) >> 2;
    const int cmax = (nch + 3) >> 2;        // uniform loop count; c0+cmax-1 <= nch-1

    const short* qb = q + ((long)b * SEQ + s0 + l15) * HEAD + quad * 8;
    short8 qf0 = *(const short8*)(qb);
    short8 qf1 = *(const short8*)(qb + 32);

    const short* kbb = k + ((long)b * SEQ + l15) * HEAD + quad * 8;
    const short* vbb = vt + ((long)b * HEAD + l15) * SEQ + quad * 8;

    floatx4 o[4];
    #pragma unroll
    for (int nt = 0; nt < 4; ++nt) o[nt] = (floatx4){0.f, 0.f, 0.f, 0.f};
    float l_i[4] = {0.f, 0.f, 0.f, 0.f};

    // prologue: load chunk c0
    short8 kf[2][2], vf[4];
    {
        const int j0 = c0 * 32;
        #pragma unroll
        for (int nt = 0; nt < 2; ++nt) {
            const short* kb = kbb + (long)(j0 + nt * 16) * HEAD;
            kf[nt][0] = *(const short8*)(kb);
            kf[nt][1] = *(const short8*)(kb + 32);
        }
        #pragma unroll
        for (int nt = 0; nt < 4; ++nt)
            vf[nt] = *(const short8*)(vbb + (long)nt * 16 * SEQ + j0);
    }

    #pragma unroll 1
    for (int i = 0; i < cmax; ++i) {
        const int c = c0 + i;
        const bool act = (c < c1);
        const int j0 = c * 32;

        // ---- prefetch next chunk (clamped; harmless if unused) ----
        const int cn = (c + 1 < nch) ? (c + 1) : (nch - 1);
        const int jn = cn * 32;
        short8 kn[2][2], vn[4];
        #pragma unroll
        for (int nt = 0; nt < 2; ++nt) {
            const short* kb = kbb + (long)(jn + nt * 16) * HEAD;
            kn[nt][0] = *(const short8*)(kb);
            kn[nt][1] = *(const short8*)(kb + 32);
        }
        #pragma unroll
        for (int nt = 0; nt < 4; ++nt)
            vn[nt] = *(const short8*)(vbb + (long)nt * 16 * SEQ + jn);

        // ---- S = Q K^T ----
        floatx4 sa[2];
        sa[0] = (floatx4){0.f, 0.f, 0.f, 0.f};
        sa[1] = (floatx4){0.f, 0.f, 0.f, 0.f};
        #pragma unroll
        for (int nt = 0; nt < 2; ++nt) {
            sa[nt] = __builtin_amdgcn_mfma_f32_16x16x32_bf16(qf0, kf[nt][0], sa[nt], 0, 0, 0);
            sa[nt] = __builtin_amdgcn_mfma_f32_16x16x32_bf16(qf1, kf[nt][1], sa[nt], 0, 0, 0);
        }

        // ---- p = exp(s/8 - 16), causal + activity mask; accumulate l ----
        #pragma unroll
        for (int r = 0; r < 4; ++r) {
            const int sq = s0 + quad * 4 + r;
            #pragma unroll
            for (int nt = 0; nt < 2; ++nt) {
                const int sk = j0 + nt * 16 + l15;
                float p = (!act || sk > sq) ? 0.f
                          : __expf(sa[nt][r] * 0.125f - 16.f);
                sa[nt][r] = p;
                l_i[r] += p;
            }
        }

        // ---- P: C-layout -> A-layout via per-wave LDS buffer ----
        #pragma unroll
        for (int nt = 0; nt < 2; ++nt)
            #pragma unroll
            for (int r = 0; r < 4; ++r)
                Plds[wv][quad * 4 + r][nt * 16 + l15] = f2bf(sa[nt][r]);
        short8 pf = *(const short8*)(&Plds[wv][l15][quad * 8]);

        // ---- O += P V ----
        #pragma unroll
        for (int nt = 0; nt < 4; ++nt)
            o[nt] = __builtin_amdgcn_mfma_f32_16x16x32_bf16(pf, vf[nt], o[nt], 0, 0, 0);

        // ---- rotate prefetch ----
        #pragma unroll
        for (int nt = 0; nt < 2; ++nt) { kf[nt][0] = kn[nt][0]; kf[nt][1] = kn[nt][1]; }
        #pragma unroll
        for (int nt = 0; nt < 4; ++nt) vf[nt] = vn[nt];
    }

    // ---- single end-of-loop l reduction ----
    #pragma unroll
    for (int msk = 1; msk <= 8; msk <<= 1) {
        #pragma unroll
        for (int r = 0; r < 4; ++r)
            l_i[r] += __shfl_xor(l_i[r], msk, 64);
    }
    if (l15 == 0) {
        #pragma unroll
        for (int r = 0; r < 4; ++r) lA[wv][quad * 4 + r] = l_i[r];
    }
    #pragma unroll
    for (int nt = 0; nt < 4; ++nt)
        #pragma unroll
        for (int r = 0; r < 4; ++r)
            oA[wv][quad * 4 + r][nt * 16 + l15] = o[nt][r];
    __syncthreads();

    // ---- cooperative epilogue: sum 4 wave-partials, coalesced float4 out ----
    {
        const int idx = threadIdx.x * 4;         // 1024 outputs, 4 per thread
        const int row = idx >> 6;
        const int col = idx & 63;
        const float l = lA[0][row] + lA[1][row] + lA[2][row] + lA[3][row];
        const float inv = 1.f / l;
        floatx4 ov;
        #pragma unroll
        for (int j = 0; j < 4; ++j)
            ov[j] = (oA[0][row][col + j] + oA[1][row][col + j]
                   + oA[2][row][col + j] + oA[3][row][col + j]) * inv;
        *(floatx4*)(out + ((long)b * SEQ + s0 + row) * HEAD + col) = ov;
    }
}

extern "C" void kernel_launch(void* const* d_in, const int* in_sizes, int n_in,
                              void* d_out, int out_size, void* d_ws, size_t ws_size,
                              hipStream_t stream) {
    const float* x  = (const float*)d_in[0];
    const float* Wk = (const float*)d_in[1];
    const float* Wq = (const float*)d_in[2];
    const float* Wv = (const float*)d_in[3];
    float* out = (float*)d_out;

    short* Wf = (short*)d_ws;                          // 384 KiB
    short* q  = Wf + 3 * HEAD * EMB;                   // 2 MiB each
    short* k  = q + (long)BATCH * SEQ * HEAD;
    short* vt = k + (long)BATCH * SEQ * HEAD;

    hipLaunchKernelGGL(wtrans_kernel, dim3(96), dim3(256), 0, stream, Wk, Wq, Wv, Wf);
    hipLaunchKernelGGL(qkv_kernel, dim3(BATCH * SEQ / 16), dim3(256), 0, stream, x, Wf, q, k, vt);
    hipLaunchKernelGGL(attn_kernel, dim3(BATCH * 128), dim3(256), 0, stream, q, k, vt, out);
}